// Round 7
// baseline (1724.908 us; speedup 1.0000x reference)
//
#include <hip/hip_runtime.h>
#include <cmath>
#include <algorithm>

#define N_NODES 8192
#define N_EDGES 131072
#define NPATHS 15
#define FPN 576          // floats per node: 9 m-rows x 64 ch (m-major) on main path
#define NODE_BLK 8       // nodes per k_aggmm block (R6: 16 -> 8 for 3 blocks/CU)
#define SWROW 968        // LDS row stride (ushorts) for weight tile (960 + 8 pad)

typedef unsigned short ushortx;
typedef unsigned int uintx;
typedef short short8 __attribute__((ext_vector_type(8)));
typedef float f32x4 __attribute__((ext_vector_type(4)));

// path table: (l1, l2, l3) in python enumeration order
constexpr int PL1[NPATHS] = {0,0,0,1,1,1,1,1,1,2,2,2,2,2,2};
constexpr int PL2[NPATHS] = {0,1,2,0,1,1,1,2,2,0,1,1,2,2,2};
constexpr int PL3[NPATHS] = {0,1,2,1,0,1,2,1,2,2,1,2,0,1,2};
constexpr int CGOFF[NPATHS] = {0,1,10,35,44,53,80,125,170,245,270,315,390,415,490};
constexpr int CGTOT = 615;
constexpr int BOFF[3] = {0,1,4};

struct CGTable { float v[CGTOT]; };

// ---------------- host-side CG construction (exact replica of reference) ----
namespace cgb {
struct C2 { double re, im; };
static inline C2 cmul(C2 a, C2 b){ return {a.re*b.re - a.im*b.im, a.re*b.im + a.im*b.re}; }
static double factd(int n){ double r=1.0; for (int i=2;i<=n;++i) r*=i; return r; }

static double cg_scalar(int j1,int m1,int j2,int m2,int j3,int m3){
  if (m1+m2 != m3) return 0.0;
  double pre = std::sqrt((2.0*j3+1.0)*factd(j1+j2-j3)*factd(j1-j2+j3)*factd(-j1+j2+j3)/factd(j1+j2+j3+1));
  pre *= std::sqrt(factd(j1+m1)*factd(j1-m1)*factd(j2+m2)*factd(j2-m2)*factd(j3+m3)*factd(j3-m3));
  double s = 0.0;
  int kmin = std::max(0, std::max(j2-j3-m1, j1+m2-j3));
  int kmax = std::min(j1+j2-j3, std::min(j1-m1, j2+m2));
  for (int k=kmin;k<=kmax;++k){
    double t = 1.0/(factd(k)*factd(j1+j2-j3-k)*factd(j1-m1-k)*factd(j2+m2-k)*factd(j3-j2+m1+k)*factd(j3-j1-m2+k));
    s += (k&1) ? -t : t;
  }
  return pre*s;
}

static void makeU(int l, C2 U[5][5]){
  double s2 = std::sqrt(0.5);
  for (int a=0;a<5;++a) for (int b=0;b<5;++b) U[a][b] = {0.0,0.0};
  for (int m=-l;m<=l;++m){
    if (m > 0){
      U[m+l][ m+l] = {((m&1)?-1.0:1.0)*s2, 0.0};
      U[m+l][-m+l] = {s2, 0.0};
    } else if (m == 0){
      U[l][l] = {1.0, 0.0};
    } else {
      U[m+l][ m+l] = {0.0, s2};
      U[m+l][-m+l] = {0.0, -((((-m)&1))?-1.0:1.0)*s2};
    }
  }
}
} // namespace cgb

static CGTable build_cg_table(){
  using namespace cgb;
  CGTable t{};
  for (int p=0;p<NPATHS;++p){
    int l1=PL1[p], l2=PL2[p], l3=PL3[p];
    int n1=2*l1+1, n2=2*l2+1, n3=2*l3+1;
    double Cc[5][5][5] = {};
    for (int i1=0;i1<n1;++i1) for (int i2=0;i2<n2;++i2){
      int m1=i1-l1, m2=i2-l2, m3=m1+m2;
      if (m3 >= -l3 && m3 <= l3) Cc[i1][i2][m3+l3] = cg_scalar(l1,m1,l2,m2,l3,m3);
    }
    C2 U1[5][5], U2[5][5], U3[5][5];
    makeU(l1,U1); makeU(l2,U2); makeU(l3,U3);
    double Wre[5][5][5]={}, Wim[5][5][5]={};
    for (int i=0;i<n1;++i) for (int j=0;j<n2;++j) for (int k=0;k<n3;++k){
      double are=0.0, aim=0.0;
      for (int a=0;a<n1;++a) for (int b=0;b<n2;++b){
        int m3 = (a-l1)+(b-l2);
        if (m3 < -l3 || m3 > l3) continue;
        double cv = Cc[a][b][m3+l3];
        if (cv == 0.0) continue;
        C2 u1c = {U1[i][a].re, -U1[i][a].im};
        C2 u2c = {U2[j][b].re, -U2[j][b].im};
        C2 tt = cmul(cmul(u1c, u2c), U3[k][m3+l3]);
        are += tt.re*cv; aim += tt.im*cv;
      }
      Wre[i][j][k]=are; Wim[i][j][k]=aim;
    }
    double nr=0.0, ni=0.0;
    for (int i=0;i<n1;++i) for (int j=0;j<n2;++j) for (int k=0;k<n3;++k){
      nr += Wre[i][j][k]*Wre[i][j][k]; ni += Wim[i][j][k]*Wim[i][j][k];
    }
    bool useRe = std::sqrt(nr) >= std::sqrt(ni);
    double nrm = std::sqrt(useRe ? nr : ni);
    double scale = std::sqrt((double)n3) / nrm;
    for (int i=0;i<n1;++i) for (int j=0;j<n2;++j) for (int k=0;k<n3;++k)
      t.v[CGOFF[p] + (i*n2+j)*n3 + k] =
        (float)((useRe ? Wre[i][j][k] : Wim[i][j][k]) * scale);
  }
  return t;
}

static const CGTable& cg_table(){ static CGTable t = build_cg_table(); return t; }

// ---------------- device helpers ----------------
__device__ __forceinline__ float siluf(float x){ return x / (1.0f + expf(-x)); }
__device__ __forceinline__ float sigmf(float x){ return 1.0f / (1.0f + expf(-x)); }
__device__ __forceinline__ ushortx f2b(float f){
  uintx u = __float_as_uint(f);
  u += 0x7fffu + ((u >> 16) & 1u);          // RNE
  return (ushortx)(u >> 16);
}
__device__ __forceinline__ float b2f(ushortx b){ return __uint_as_float(((uintx)b) << 16); }

// ---------------- main-path kernels (m-major feats) ----------------
__global__ __launch_bounds__(64) void k_init(const int* __restrict__ species,
    const float* __restrict__ embed, const float* __restrict__ wproj,
    float* __restrict__ feats)
{
  const int n = blockIdx.x, c = threadIdx.x;
  const int sp = species[n];
  float acc = 0.f;
  #pragma unroll
  for (int q=0;q<32;++q) acc += embed[sp*32+q]*wproj[q*64+c];
  feats[n*FPN + c] = acc;
  #pragma unroll
  for (int r=1;r<9;++r) feats[n*FPN + r*64 + c] = 0.f;
}

// m-major feats -> reference output layout (ch-major within each l block)
__global__ __launch_bounds__(64) void k_out_t(const float* __restrict__ feats,
                                              float* __restrict__ out)
{
  const int n = blockIdx.x, c = threadIdx.x;
  const float* f = feats + (size_t)n*FPN;
  float* o = out + (size_t)n*FPN;
  o[c] = f[c];
  #pragma unroll
  for (int mm=0;mm<3;++mm) o[64 + c*3 + mm] = f[(1+mm)*64 + c] * 0.5f;
  #pragma unroll
  for (int mm=0;mm<5;++mm) o[256 + c*5 + mm] = f[(4+mm)*64 + c] * 0.25f;
}

// ---------------- sorting ----------------
__global__ __launch_bounds__(256) void k_hist(const int* __restrict__ receivers,
                                              int* __restrict__ cnt)
{
  int e = blockIdx.x*256 + threadIdx.x;
  atomicAdd(&cnt[receivers[e]], 1);
}

__global__ __launch_bounds__(1024) void k_scan(const int* __restrict__ cnt,
    int* __restrict__ row_start, int* __restrict__ cursor)
{
  __shared__ int part[1024];
  const int t = threadIdx.x;
  int loc[8];
  #pragma unroll
  for (int i=0;i<8;++i) loc[i] = cnt[t*8+i];
  int sum = 0;
  #pragma unroll
  for (int i=0;i<8;++i) sum += loc[i];
  part[t] = sum;
  __syncthreads();
  for (int off=1; off<1024; off<<=1){
    int x = (t >= off) ? part[t-off] : 0;
    __syncthreads();
    part[t] += x;
    __syncthreads();
  }
  int run = (t > 0) ? part[t-1] : 0;
  #pragma unroll
  for (int i=0;i<8;++i){
    row_start[t*8+i] = run;
    cursor[t*8+i]    = run;
    run += loc[i];
  }
  if (t == 1023) row_start[8192] = run;
}

__global__ __launch_bounds__(256) void k_scatter(const int* __restrict__ receivers,
    int* __restrict__ cursor, int* __restrict__ perm)
{
  int e = blockIdx.x*256 + threadIdx.x;
  int r = receivers[e];
  int pos = atomicAdd(&cursor[r], 1);
  perm[pos] = e;
}

// geometry in RECEIVER-SORTED order: i = sorted index, e = perm[i]
__global__ __launch_bounds__(256) void k_geom(const float* __restrict__ pos,
    const int* __restrict__ senders, const int* __restrict__ receivers,
    const int* __restrict__ perm,
    float* __restrict__ sh8s, float* __restrict__ d_s,
    int* __restrict__ send_s, int* __restrict__ recv_s)
{
  const int i = blockIdx.x*256 + threadIdx.x;
  const int e = perm[i];
  const int s = senders[e], r = receivers[e];
  send_s[i] = s;
  recv_s[i] = r;
  float rx = (pos[r*3+0] - pos[s*3+0]) * 0.2f;
  float ry = (pos[r*3+1] - pos[s*3+1]) * 0.2f;
  float rz = (pos[r*3+2] - pos[s*3+2]) * 0.2f;
  float d  = sqrtf(rx*rx + ry*ry + rz*rz);
  d_s[i] = d;
  float iv = 1.0f / fmaxf(d, 1e-6f);
  float x = rx*iv, y = ry*iv, z = rz*iv;
  const float s3   = 1.7320508075688772f;
  const float s15  = 3.8729833462074170f;
  const float s5h  = 1.1180339887498949f;
  const float s15h = 1.9364916731037085f;
  sh8s[i*8+0] = s3*y;
  sh8s[i*8+1] = s3*z;
  sh8s[i*8+2] = s3*x;
  sh8s[i*8+3] = s15*x*y;
  sh8s[i*8+4] = s15*y*z;
  sh8s[i*8+5] = s5h*(3.f*z*z - 1.f);
  sh8s[i*8+6] = s15*x*z;
  sh8s[i*8+7] = s15h*(x*x - y*y);
}

// radial MLP in sorted order; 8 edges/block (4 waves x 2); lane = hidden unit
__global__ __launch_bounds__(256) void k_mlp(
    const float* __restrict__ d_s,
    const float* __restrict__ w1, const float* __restrict__ b1,
    const float* __restrict__ w2, const float* __restrict__ b2,
    ushortx* __restrict__ h2p)
{
  __shared__ float s_w2[4096];
  __shared__ float s_h1[4*64];
  const int tid = threadIdx.x, wv = tid>>6, lane = tid&63;
  const float PI = 3.14159265358979323846f;
  for (int i=tid;i<4096;i+=256) s_w2[i] = w2[i];
  __syncthreads();
  #pragma unroll
  for (int ee=0; ee<2; ++ee){
    const int i = blockIdx.x*8 + wv*2 + ee;
    const float d = d_s[i];
    float xr = fminf(fmaxf(d, 1e-4f), 1.0f);
    float ixr = 1.0f/xr;
    float acc = b1[lane];
    #pragma unroll
    for (int q=0;q<8;++q){
      float bs = 1.4142135623730951f * sinf((float)(q+1)*PI*xr) * ixr;
      acc = fmaf(bs, w1[q*64+lane], acc);
    }
    s_h1[wv*64+lane] = siluf(acc);
    __syncthreads();
    float acc2 = b2[lane];
    #pragma unroll
    for (int k=0;k<64;++k) acc2 = fmaf(s_h1[wv*64+k], s_w2[k*64+lane], acc2);
    float dc = fminf(fmaxf(d, 0.f), 1.f);
    float cut = 0.5f*(cosf(PI*dc) + 1.f);
    float h2 = siluf(acc2) * cut * 0.25f;     // fold envelope * 1/sqrt(avg_nn)
    h2p[(size_t)i*64+lane] = f2b(h2);
    __syncthreads();
  }
}

// w3 transpose + bf16 cast: w3t[n*64+k] = bf16(w3[k*960+n])
__global__ __launch_bounds__(256) void k_w3t(const float* __restrict__ w3,
                                             ushortx* __restrict__ w3t)
{
  int g = blockIdx.x*256 + threadIdx.x;   // g over 61440
  int n = g >> 6, k = g & 63;
  w3t[g] = f2b(w3[k*960 + n]);
}

// fused: MFMA edge-weight GEMM + CG tensor product + per-node-range
// aggregation (LDS) + node update.  One block per 8 consecutive nodes.
// R5 structure unchanged except NODE_BLK 16->8: LDS 70.1->51.7 KB so
// 3 blocks/CU instead of 2 (no VGPR cap, no channel split -- the R3/R4
// poison pills are deliberately absent).
__global__ __launch_bounds__(256) void k_aggmm(
    const float* __restrict__ featsIn, float* __restrict__ featsOut,
    const ushortx* __restrict__ h2p, const ushortx* __restrict__ w3t,
    const float* __restrict__ sh8s, const int* __restrict__ send_s,
    const int* __restrict__ recv_s, const int* __restrict__ rowst,
    const float* __restrict__ lin, const float* __restrict__ gw,
    const float* __restrict__ gb, const CGTable cg)
{
  __shared__ float   s_agg[NODE_BLK*FPN];   // 18432 B  (m-major per node)
  __shared__ ushortx s_w[16*SWROW];         // 30976 B
  __shared__ ushortx s_a[16*72];            //  2304 B

  const int tid  = threadIdx.x;
  const int wv   = tid >> 6;
  const int lane = tid & 63;
  const int n0   = blockIdx.x * NODE_BLK;
  const int beg  = rowst[n0];
  const int end  = rowst[n0 + NODE_BLK];

  for (int k = tid; k < NODE_BLK*FPN; k += 256) s_agg[k] = 0.f;
  __syncthreads();

  const int q = lane >> 4, mrow = lane & 15;

  for (int ebeg = beg; ebeg < end; ebeg += 16){
    // --- stage A tile (16 edges x 64 k, bf16) ---
    {
      int er = tid >> 4, seg = tid & 15;
      int i = ebeg + er;
      if (i >= end) i = end - 1;            // clamp: garbage rows unused later
      *(uint2*)&s_a[er*72 + seg*4] =
        *(const uint2*)&h2p[(size_t)i*64 + seg*4];
    }
    __syncthreads();

    // --- MFMA GEMM: wave wv covers cols wv*240 .. wv*240+239 ---
    short8 a0 = *(const short8*)&s_a[mrow*72 +      q*8];
    short8 a1 = *(const short8*)&s_a[mrow*72 + 32 + q*8];
    #pragma unroll
    for (int nt=0; nt<15; ++nt){
      const int col = wv*240 + nt*16 + mrow;     // B col n == C col
      short8 b0 = *(const short8*)&w3t[(size_t)col*64 +      q*8];
      short8 b1 = *(const short8*)&w3t[(size_t)col*64 + 32 + q*8];
      f32x4 acc = {0.f,0.f,0.f,0.f};
      acc = __builtin_amdgcn_mfma_f32_16x16x32_bf16(a0, b0, acc, 0, 0, 0);
      acc = __builtin_amdgcn_mfma_f32_16x16x32_bf16(a1, b1, acc, 0, 0, 0);
      #pragma unroll
      for (int r=0;r<4;++r)
        s_w[(q*4+r)*SWROW + col] = f2b(acc[r]);  // C row = (lane>>4)*4 + reg
    }
    __syncthreads();

    // --- CG tensor product; wave wv owns slots wv*4+ee; lane = channel ---
    #pragma unroll
    for (int ee=0; ee<4; ++ee){
      const int slot = wv*4 + ee;
      const int i = ebeg + slot;
      if (i < end){
        const int s  = send_s[i];
        const int rl = recv_s[i] - n0;          // local node in [0,NODE_BLK)
        const float* fb = featsIn + (size_t)s*FPN;
        float X[9];
        #pragma unroll
        for (int r=0;r<9;++r) X[r] = fb[r*64 + lane];   // coalesced 256B rows
        float S[9];
        S[0] = 1.f;
        #pragma unroll
        for (int jj=0;jj<8;++jj) S[1+jj] = sh8s[(size_t)i*8+jj];
        float w[NPATHS];
        #pragma unroll
        for (int p=0;p<NPATHS;++p) w[p] = b2f(s_w[slot*SWROW + p*64 + lane]);
        float m[9];
        #pragma unroll
        for (int k=0;k<9;++k) m[k] = 0.f;
        #pragma unroll
        for (int p=0;p<NPATHS;++p){
          const int l1=PL1[p], l2=PL2[p], l3=PL3[p];
          const int n2=2*l2+1, n3=2*l3+1;
          const float wp_ = w[p];
          #pragma unroll
          for (int ii=0;ii<2*l1+1;++ii){
            #pragma unroll
            for (int jj=0;jj<n2;++jj){
              float t = wp_ * X[BOFF[l1]+ii] * S[BOFF[l2]+jj];
              #pragma unroll
              for (int k=0;k<n3;++k)
                m[BOFF[l3]+k] = fmaf(cg.v[CGOFF[p] + (ii*n2+jj)*n3 + k], t, m[BOFF[l3]+k]);
            }
          }
        }
        float* ab = s_agg + rl*FPN;
        #pragma unroll
        for (int r=0;r<9;++r) atomicAdd(&ab[r*64 + lane], m[r]);   // stride-1
      }
    }
    __syncthreads();
  }

  // --- node update: wave wv handles nodes wv*2 .. wv*2+1 ---
  #pragma unroll
  for (int k=0;k<2;++k){
    const int ln = wv*2 + k;
    const int n  = n0 + ln;
    const float* ag = s_agg + ln*FPN;
    float y[9];
    #pragma unroll
    for (int j=0;j<9;++j) y[j] = 0.f;
    for (int c=0;c<64;++c){
      float l0 = lin[          c*64 + lane];
      float l1 = lin[4096    + c*64 + lane];
      float l2 = lin[8192    + c*64 + lane];
      y[0] = fmaf(ag[c], l0, y[0]);
      #pragma unroll
      for (int mm=0;mm<3;++mm) y[1+mm] = fmaf(ag[(1+mm)*64 + c], l1, y[1+mm]);
      #pragma unroll
      for (int mm=0;mm<5;++mm) y[4+mm] = fmaf(ag[(4+mm)*64 + c], l2, y[4+mm]);
    }
    const size_t base = (size_t)n*FPN;
    float f0 = featsIn[base + lane] + siluf(y[0]);
    featsOut[base + lane] = f0;
    float a1 = gb[lane], a2 = gb[64 + lane];
    for (int c=0;c<64;++c){
      float fc = __shfl(f0, c);
      a1 = fmaf(fc, gw[        c*64 + lane], a1);
      a2 = fmaf(fc, gw[4096 +  c*64 + lane], a2);
    }
    float g1 = sigmf(a1), g2 = sigmf(a2);
    #pragma unroll
    for (int mm=0;mm<3;++mm)
      featsOut[base + (1+mm)*64 + lane] = featsIn[base + (1+mm)*64 + lane] + g1*y[1+mm];
    #pragma unroll
    for (int mm=0;mm<5;++mm)
      featsOut[base + (4+mm)*64 + lane] = featsIn[base + (4+mm)*64 + lane] + g2*y[4+mm];
  }
}

// ---------------- fallback (round-0 verified path, ch-major layout) --------
__global__ __launch_bounds__(64) void k_init_fb(const int* __restrict__ species,
    const float* __restrict__ embed, const float* __restrict__ wproj,
    float* __restrict__ feats)
{
  const int n = blockIdx.x, c = threadIdx.x;
  const int sp = species[n];
  float acc = 0.f;
  #pragma unroll
  for (int q=0;q<32;++q) acc += embed[sp*32+q]*wproj[q*64+c];
  feats[n*FPN + c] = acc;
  #pragma unroll
  for (int j=0;j<8;++j) feats[n*FPN + 64 + j*64 + c] = 0.f;
}

__global__ __launch_bounds__(256) void k_out_fb(const float* __restrict__ feats,
                                                float* __restrict__ out)
{
  const int n = blockIdx.x;
  for (int j = threadIdx.x; j < FPN; j += 256){
    float sc = (j < 64) ? 1.0f : ((j < 256) ? 0.5f : 0.25f);
    out[n*FPN + j] = feats[n*FPN + j] * sc;
  }
}

__global__ __launch_bounds__(256) void k_edge_fb(
    const float* __restrict__ pos,
    const int* __restrict__ senders, const int* __restrict__ receivers,
    const float* __restrict__ w1, const float* __restrict__ b1,
    const float* __restrict__ w2, const float* __restrict__ b2,
    const float* __restrict__ w3,
    const float* __restrict__ feats, float* __restrict__ agg,
    const CGTable cg)
{
  __shared__ float s_h1[16*64];
  __shared__ float s_h2[16*64];
  __shared__ float s_w3[8*960];
  __shared__ float s_sh[16][8];
  __shared__ float s_cut[16];

  const int tid  = threadIdx.x;
  const int wave = tid >> 6;
  const int lane = tid & 63;
  const int ebase = blockIdx.x * 16;
  const float PI = 3.14159265358979323846f;

  #pragma unroll
  for (int ee=0; ee<4; ++ee){
    const int slot = wave*4 + ee;
    const int e = ebase + slot;
    const int s = senders[e], r = receivers[e];
    float rx = (pos[r*3+0] - pos[s*3+0]) * 0.2f;
    float ry = (pos[r*3+1] - pos[s*3+1]) * 0.2f;
    float rz = (pos[r*3+2] - pos[s*3+2]) * 0.2f;
    float d  = sqrtf(rx*rx + ry*ry + rz*rz);
    float iv = 1.0f / fmaxf(d, 1e-6f);
    float x = rx*iv, y = ry*iv, z = rz*iv;
    if (lane == 0){
      const float s3   = 1.7320508075688772f;
      const float s15  = 3.8729833462074170f;
      const float s5h  = 1.1180339887498949f;
      const float s15h = 1.9364916731037085f;
      s_sh[slot][0] = s3*y;  s_sh[slot][1] = s3*z;  s_sh[slot][2] = s3*x;
      s_sh[slot][3] = s15*x*y; s_sh[slot][4] = s15*y*z;
      s_sh[slot][5] = s5h*(3.f*z*z - 1.f);
      s_sh[slot][6] = s15*x*z; s_sh[slot][7] = s15h*(x*x - y*y);
      float dc = fminf(fmaxf(d, 0.f), 1.f);
      s_cut[slot] = 0.5f*(cosf(PI*dc) + 1.f);
    }
    float xr = fminf(fmaxf(d, 1e-4f), 1.0f);
    float ixr = 1.0f/xr;
    float acc = b1[lane];
    #pragma unroll
    for (int q=0;q<8;++q)
      acc += 1.4142135623730951f * sinf((float)(q+1)*PI*xr) * ixr * w1[q*64 + lane];
    s_h1[slot*64 + lane] = siluf(acc);
  }
  __syncthreads();
  #pragma unroll
  for (int ee=0; ee<4; ++ee){
    const int slot = wave*4 + ee;
    float acc = b2[lane];
    #pragma unroll
    for (int k=0;k<64;++k) acc += s_h1[slot*64+k] * w2[k*64+lane];
    s_h2[slot*64+lane] = siluf(acc);
  }
  __syncthreads();

  float wgt[NPATHS][4];
  #pragma unroll
  for (int p=0;p<NPATHS;++p){ wgt[p][0]=wgt[p][1]=wgt[p][2]=wgt[p][3]=0.f; }
  for (int kc=0;kc<8;++kc){
    #pragma unroll
    for (int rr=0;rr<8;++rr){
      #pragma unroll
      for (int jj=0;jj<4;++jj){
        int col = jj*256 + tid;
        if (col < 960) s_w3[rr*960+col] = w3[(kc*8+rr)*960+col];
      }
    }
    __syncthreads();
    #pragma unroll
    for (int kk=0;kk<8;++kk){
      float h2v[4];
      #pragma unroll
      for (int ee=0;ee<4;++ee) h2v[ee] = s_h2[(wave*4+ee)*64 + kc*8+kk];
      #pragma unroll
      for (int p=0;p<NPATHS;++p){
        float wv = s_w3[kk*960 + p*64 + lane];
        #pragma unroll
        for (int ee=0;ee<4;++ee) wgt[p][ee] = fmaf(h2v[ee], wv, wgt[p][ee]);
      }
    }
    __syncthreads();
  }
  #pragma unroll
  for (int ee=0;ee<4;++ee){
    float f = s_cut[wave*4+ee] * 0.25f;
    #pragma unroll
    for (int p=0;p<NPATHS;++p) wgt[p][ee] *= f;
  }
  #pragma unroll
  for (int ee=0;ee<4;++ee){
    const int slot = wave*4 + ee;
    const int e = ebase + slot;
    const int s = senders[e];
    const int r = receivers[e];
    const int sb = s*FPN;
    float X[9], S[9], msg[9];
    X[0] = feats[sb + lane];
    #pragma unroll
    for (int mm=0;mm<3;++mm) X[1+mm] = feats[sb + 64  + lane*3 + mm];
    #pragma unroll
    for (int mm=0;mm<5;++mm) X[4+mm] = feats[sb + 256 + lane*5 + mm];
    S[0] = 1.f;
    #pragma unroll
    for (int j=0;j<8;++j) S[1+j] = s_sh[slot][j];
    #pragma unroll
    for (int k=0;k<9;++k) msg[k] = 0.f;
    #pragma unroll
    for (int p=0;p<NPATHS;++p){
      const int l1=PL1[p], l2=PL2[p], l3=PL3[p];
      const int n2=2*l2+1, n3=2*l3+1;
      const float wp = wgt[p][ee];
      #pragma unroll
      for (int i=0;i<2*l1+1;++i){
        #pragma unroll
        for (int j=0;j<n2;++j){
          float t = wp * X[BOFF[l1]+i] * S[BOFF[l2]+j];
          #pragma unroll
          for (int k=0;k<n3;++k)
            msg[BOFF[l3]+k] = fmaf(cg.v[CGOFF[p] + (i*n2+j)*n3 + k], t, msg[BOFF[l3]+k]);
        }
      }
    }
    const int rb = r*FPN;
    unsafeAtomicAdd(&agg[rb + lane], msg[0]);
    #pragma unroll
    for (int mm=0;mm<3;++mm) unsafeAtomicAdd(&agg[rb + 64  + lane*3 + mm], msg[1+mm]);
    #pragma unroll
    for (int mm=0;mm<5;++mm) unsafeAtomicAdd(&agg[rb + 256 + lane*5 + mm], msg[4+mm]);
  }
}

__global__ __launch_bounds__(64) void k_node_fb(
    float* __restrict__ feats, const float* __restrict__ agg,
    const float* __restrict__ lin, const float* __restrict__ gw,
    const float* __restrict__ gb)
{
  __shared__ float sf0[64];
  const int n = blockIdx.x, d = threadIdx.x;
  const int base = n*FPN;
  float y[9];
  #pragma unroll
  for (int k=0;k<9;++k) y[k]=0.f;
  for (int c=0;c<64;++c){
    float l0 = lin[          c*64 + d];
    float l1 = lin[4096    + c*64 + d];
    float l2 = lin[8192    + c*64 + d];
    y[0] = fmaf(agg[base + c], l0, y[0]);
    #pragma unroll
    for (int mm=0;mm<3;++mm) y[1+mm] = fmaf(agg[base + 64  + c*3 + mm], l1, y[1+mm]);
    #pragma unroll
    for (int mm=0;mm<5;++mm) y[4+mm] = fmaf(agg[base + 256 + c*5 + mm], l2, y[4+mm]);
  }
  float f0 = feats[base + d] + siluf(y[0]);
  feats[base + d] = f0;
  sf0[d] = f0;
  __syncthreads();
  {
    float acc = gb[d];
    for (int c=0;c<64;++c) acc = fmaf(sf0[c], gw[c*64 + d], acc);
    float g = sigmf(acc);
    #pragma unroll
    for (int mm=0;mm<3;++mm) feats[base + 64 + d*3 + mm] += g*y[1+mm];
  }
  {
    float acc = gb[64 + d];
    for (int c=0;c<64;++c) acc = fmaf(sf0[c], gw[4096 + c*64 + d], acc);
    float g = sigmf(acc);
    #pragma unroll
    for (int mm=0;mm<5;++mm) feats[base + 256 + d*5 + mm] += g*y[4+mm];
  }
}

// ---------------- launch ----------------
extern "C" void kernel_launch(void* const* d_in, const int* in_sizes, int n_in,
                              void* d_out, int out_size, void* d_ws, size_t ws_size,
                              hipStream_t stream)
{
  const float* pos      = (const float*)d_in[0];
  const int*   species  = (const int*)  d_in[1];
  const int*   senders  = (const int*)  d_in[2];
  const int*   receivers= (const int*)  d_in[3];
  const float* embed    = (const float*)d_in[4];
  const float* wproj    = (const float*)d_in[5];
  const float* w1       = (const float*)d_in[6];
  const float* b1       = (const float*)d_in[7];
  const float* w2       = (const float*)d_in[8];
  const float* b2       = (const float*)d_in[9];
  const float* w3       = (const float*)d_in[10];
  const float* lin      = (const float*)d_in[11];
  const float* gw       = (const float*)d_in[12];
  const float* gb       = (const float*)d_in[13];

  const CGTable& cg = cg_table();

  // ws layout (main path) — ~61 MB total
  char* p = (char*)d_ws;
  size_t off = 0;
  auto alloc = [&](size_t bytes)->char*{
    char* r = p + off;
    off += (bytes + 255) & ~(size_t)255;
    return r;
  };
  float*   featsA  = (float*)  alloc((size_t)N_NODES*FPN*4);
  float*   featsB  = (float*)  alloc((size_t)N_NODES*FPN*4);
  int*     cnt     = (int*)    alloc(N_NODES*4);
  int*     cursor  = (int*)    alloc(N_NODES*4);
  int*     rowst   = (int*)    alloc((N_NODES+1)*4);
  int*     perm    = (int*)    alloc((size_t)N_EDGES*4);
  int*     send_s  = (int*)    alloc((size_t)N_EDGES*4);
  int*     recv_s  = (int*)    alloc((size_t)N_EDGES*4);
  float*   d_sArr  = (float*)  alloc((size_t)N_EDGES*4);
  float*   sh8s    = (float*)  alloc((size_t)N_EDGES*8*4);
  ushortx* h2p     = (ushortx*)alloc((size_t)N_EDGES*64*2);
  ushortx* w3t     = (ushortx*)alloc((size_t)960*64*2);
  const size_t need_main = off;

  if (ws_size >= need_main){
    hipMemsetAsync(cnt, 0, N_NODES*4, stream);
    hipLaunchKernelGGL(k_hist,    dim3(N_EDGES/256), dim3(256), 0, stream, receivers, cnt);
    hipLaunchKernelGGL(k_scan,    dim3(1), dim3(1024), 0, stream, cnt, rowst, cursor);
    hipLaunchKernelGGL(k_scatter, dim3(N_EDGES/256), dim3(256), 0, stream, receivers, cursor, perm);
    hipLaunchKernelGGL(k_geom,    dim3(N_EDGES/256), dim3(256), 0, stream,
                       pos, senders, receivers, perm, sh8s, d_sArr, send_s, recv_s);
    hipLaunchKernelGGL(k_init,    dim3(N_NODES), dim3(64), 0, stream,
                       species, embed, wproj, featsA);
    for (int L=0; L<2; ++L){
      const float* fin  = (L == 0) ? featsA : featsB;
      float*       fout = (L == 0) ? featsB : featsA;
      hipLaunchKernelGGL(k_mlp,  dim3(N_EDGES/8), dim3(256), 0, stream,
                         d_sArr, w1 + L*512, b1 + L*64, w2 + L*4096, b2 + L*64, h2p);
      hipLaunchKernelGGL(k_w3t,  dim3(240), dim3(256), 0, stream, w3 + (size_t)L*61440, w3t);
      hipLaunchKernelGGL(k_aggmm, dim3(N_NODES/NODE_BLK), dim3(256), 0, stream,
                         fin, fout, h2p, w3t, sh8s, send_s, recv_s, rowst,
                         lin + L*3*64*64, gw + L*2*64*64, gb + L*2*64, cg);
    }
    hipLaunchKernelGGL(k_out_t, dim3(N_NODES), dim3(64), 0, stream, featsA, (float*)d_out);
  } else {
    // fallback: round-0 verified path (needs only feats + agg = 37.7 MB)
    float* feats = (float*)d_ws;
    float* agg   = feats + (size_t)N_NODES*FPN;
    hipLaunchKernelGGL(k_init_fb, dim3(N_NODES), dim3(64), 0, stream,
                       species, embed, wproj, feats);
    for (int L=0; L<2; ++L){
      hipMemsetAsync(agg, 0, (size_t)N_NODES*FPN*sizeof(float), stream);
      hipLaunchKernelGGL(k_edge_fb, dim3(N_EDGES/16), dim3(256), 0, stream,
                         pos, senders, receivers,
                         w1 + L*512, b1 + L*64, w2 + L*4096, b2 + L*64,
                         w3 + (size_t)L*61440, feats, agg, cg);
      hipLaunchKernelGGL(k_node_fb, dim3(N_NODES), dim3(64), 0, stream,
                         feats, agg, lin + L*3*64*64, gw + L*2*64*64, gb + L*2*64);
    }
    hipLaunchKernelGGL(k_out_fb, dim3(N_NODES), dim3(256), 0, stream, feats, (float*)d_out);
  }
}

// Round 8
// 1409.147 us; speedup vs baseline: 1.2241x; 1.2241x over previous
//
#include <hip/hip_runtime.h>
#include <cmath>
#include <algorithm>

#define N_NODES 8192
#define N_EDGES 131072
#define NPATHS 15
#define FPN 576          // floats per node: 9 m-rows x 64 ch (m-major) on main path
#define NODE_BLK 8       // nodes per k_aggmm block
#define SWROW 968        // LDS row stride (ushorts) for weight tile (960 + 8 pad)

typedef unsigned short ushortx;
typedef unsigned int uintx;
typedef short short8 __attribute__((ext_vector_type(8)));
typedef float f32x4 __attribute__((ext_vector_type(4)));

// path table: (l1, l2, l3) in python enumeration order
constexpr int PL1[NPATHS] = {0,0,0,1,1,1,1,1,1,2,2,2,2,2,2};
constexpr int PL2[NPATHS] = {0,1,2,0,1,1,1,2,2,0,1,1,2,2,2};
constexpr int PL3[NPATHS] = {0,1,2,1,0,1,2,1,2,2,1,2,0,1,2};
constexpr int CGOFF[NPATHS] = {0,1,10,35,44,53,80,125,170,245,270,315,390,415,490};
constexpr int CGTOT = 615;
constexpr int BOFF[3] = {0,1,4};

struct CGTable { float v[CGTOT]; };

// ---------------- constexpr CG construction (exact replica of reference) ----
// All math in double, compile-time.  csqrt = Newton fixpoint (agrees with IEEE
// sqrt to <=1 ulp; invisible after fp32 cast).
constexpr double cfact(int n){ double r=1.0; for (int i=2;i<=n;++i) r*=i; return r; }
constexpr double csqrt(double x){
  if (x <= 0.0) return 0.0;
  double g = x < 1.0 ? 1.0 : x, p = 0.0;
  while (g != p){ p = g; g = 0.5*(g + x/g); }
  return g;
}
constexpr int cmax2(int a,int b){ return a>b?a:b; }
constexpr int cmin2(int a,int b){ return a<b?a:b; }

constexpr double cg_scalar_c(int j1,int m1,int j2,int m2,int j3,int m3){
  if (m1+m2 != m3) return 0.0;
  double pre = csqrt((2.0*j3+1.0)*cfact(j1+j2-j3)*cfact(j1-j2+j3)*cfact(-j1+j2+j3)/cfact(j1+j2+j3+1));
  pre *= csqrt(cfact(j1+m1)*cfact(j1-m1)*cfact(j2+m2)*cfact(j2-m2)*cfact(j3+m3)*cfact(j3-m3));
  double s = 0.0;
  int kmin = cmax2(0, cmax2(j2-j3-m1, j1+m2-j3));
  int kmax = cmin2(j1+j2-j3, cmin2(j1-m1, j2+m2));
  for (int k=kmin;k<=kmax;++k){
    double t = 1.0/(cfact(k)*cfact(j1+j2-j3-k)*cfact(j1-m1-k)*cfact(j2+m2-k)*cfact(j3-j2+m1+k)*cfact(j3-j1-m2+k));
    s += (k&1) ? -t : t;
  }
  return pre*s;
}

struct C2c { double re, im; };
constexpr C2c Uelem(int l, int a, int b){
  // row index a (m = a-l), col index b; mirrors reference _U_real
  const double s2 = csqrt(0.5);
  const int m = a - l;
  C2c z{0.0, 0.0};
  if (m > 0){
    if (b ==  m+l) z = {((m&1)?-1.0:1.0)*s2, 0.0};
    else if (b == -m+l) z = {s2, 0.0};
  } else if (m == 0){
    if (b == l) z = {1.0, 0.0};
  } else {
    if (b ==  m+l) z = {0.0, s2};
    else if (b == -m+l) z = {0.0, -((((-m)&1))?-1.0:1.0)*s2};
  }
  return z;
}

constexpr CGTable build_cg(){
  CGTable t{};
  for (int p=0;p<NPATHS;++p){
    const int l1=PL1[p], l2=PL2[p], l3=PL3[p];
    const int n1=2*l1+1, n2=2*l2+1, n3=2*l3+1;
    double Cc[5][5][5] = {};
    for (int i1=0;i1<n1;++i1) for (int i2=0;i2<n2;++i2){
      int m1=i1-l1, m2=i2-l2, m3=m1+m2;
      if (m3 >= -l3 && m3 <= l3) Cc[i1][i2][m3+l3] = cg_scalar_c(l1,m1,l2,m2,l3,m3);
    }
    double Wre[5][5][5]={}, Wim[5][5][5]={};
    for (int i=0;i<n1;++i) for (int j=0;j<n2;++j) for (int k=0;k<n3;++k){
      double are=0.0, aim=0.0;
      for (int a=0;a<n1;++a) for (int b=0;b<n2;++b){
        int m3 = (a-l1)+(b-l2);
        if (m3 < -l3 || m3 > l3) continue;
        double cv = Cc[a][b][m3+l3];
        if (cv == 0.0) continue;
        C2c u1 = Uelem(l1,i,a);  u1.im = -u1.im;   // conj
        C2c u2 = Uelem(l2,j,b);  u2.im = -u2.im;   // conj
        C2c u3 = Uelem(l3,k,m3+l3);
        // tt = (u1*u2)*u3
        C2c u12{u1.re*u2.re - u1.im*u2.im, u1.re*u2.im + u1.im*u2.re};
        C2c tt {u12.re*u3.re - u12.im*u3.im, u12.re*u3.im + u12.im*u3.re};
        are += tt.re*cv; aim += tt.im*cv;
      }
      Wre[i][j][k]=are; Wim[i][j][k]=aim;
    }
    double nr=0.0, ni=0.0;
    for (int i=0;i<n1;++i) for (int j=0;j<n2;++j) for (int k=0;k<n3;++k){
      nr += Wre[i][j][k]*Wre[i][j][k]; ni += Wim[i][j][k]*Wim[i][j][k];
    }
    const bool useRe = csqrt(nr) >= csqrt(ni);
    const double nrm = csqrt(useRe ? nr : ni);
    const double scale = csqrt((double)n3) / nrm;
    for (int i=0;i<n1;++i) for (int j=0;j<n2;++j) for (int k=0;k<n3;++k)
      t.v[CGOFF[p] + (i*n2+j)*n3 + k] =
        (float)((useRe ? Wre[i][j][k] : Wim[i][j][k]) * scale);
  }
  return t;
}

inline constexpr CGTable CGC = build_cg();   // compile-time table; zeros fold

// ---------------- device helpers ----------------
__device__ __forceinline__ float siluf(float x){ return x / (1.0f + expf(-x)); }
__device__ __forceinline__ float sigmf(float x){ return 1.0f / (1.0f + expf(-x)); }
__device__ __forceinline__ ushortx f2b(float f){
  uintx u = __float_as_uint(f);
  u += 0x7fffu + ((u >> 16) & 1u);          // RNE
  return (ushortx)(u >> 16);
}
__device__ __forceinline__ float b2f(ushortx b){ return __uint_as_float(((uintx)b) << 16); }

// sparse CG tensor-product for one (l1,l2) combo covering paths P0..P0+NP-1.
// CGC is constexpr: zero coefficients and their feeding muls dead-code out;
// nonzero coefficients become literal immediates.
template<int L1, int L2, int P0, int NP>
__device__ __forceinline__ void tp_combo(const float* __restrict__ X,
                                         const float* __restrict__ S,
                                         const float* __restrict__ w,
                                         float* __restrict__ m)
{
  #pragma unroll
  for (int i=0;i<2*L1+1;++i){
    #pragma unroll
    for (int j=0;j<2*L2+1;++j){
      const float xs = X[BOFF[L1]+i] * S[BOFF[L2]+j];
      #pragma unroll
      for (int pp=0;pp<NP;++pp){
        const int p  = P0 + pp;
        const int l3 = PL3[p];
        const int n3 = 2*l3+1;
        const float t = w[p] * xs;
        #pragma unroll
        for (int k=0;k<n3;++k){
          const float c = CGC.v[CGOFF[p] + (i*(2*L2+1)+j)*n3 + k];
          if (c != 0.0f) m[BOFF[l3]+k] = fmaf(c, t, m[BOFF[l3]+k]);
        }
      }
    }
  }
}

// ---------------- main-path kernels (m-major feats) ----------------
__global__ __launch_bounds__(64) void k_init(const int* __restrict__ species,
    const float* __restrict__ embed, const float* __restrict__ wproj,
    float* __restrict__ feats)
{
  const int n = blockIdx.x, c = threadIdx.x;
  const int sp = species[n];
  float acc = 0.f;
  #pragma unroll
  for (int q=0;q<32;++q) acc += embed[sp*32+q]*wproj[q*64+c];
  feats[n*FPN + c] = acc;
  #pragma unroll
  for (int r=1;r<9;++r) feats[n*FPN + r*64 + c] = 0.f;
}

// m-major feats -> reference output layout (ch-major within each l block)
__global__ __launch_bounds__(64) void k_out_t(const float* __restrict__ feats,
                                              float* __restrict__ out)
{
  const int n = blockIdx.x, c = threadIdx.x;
  const float* f = feats + (size_t)n*FPN;
  float* o = out + (size_t)n*FPN;
  o[c] = f[c];
  #pragma unroll
  for (int mm=0;mm<3;++mm) o[64 + c*3 + mm] = f[(1+mm)*64 + c] * 0.5f;
  #pragma unroll
  for (int mm=0;mm<5;++mm) o[256 + c*5 + mm] = f[(4+mm)*64 + c] * 0.25f;
}

// ---------------- sorting ----------------
__global__ __launch_bounds__(256) void k_hist(const int* __restrict__ receivers,
                                              int* __restrict__ cnt)
{
  int e = blockIdx.x*256 + threadIdx.x;
  atomicAdd(&cnt[receivers[e]], 1);
}

__global__ __launch_bounds__(1024) void k_scan(const int* __restrict__ cnt,
    int* __restrict__ row_start, int* __restrict__ cursor)
{
  __shared__ int part[1024];
  const int t = threadIdx.x;
  int loc[8];
  #pragma unroll
  for (int i=0;i<8;++i) loc[i] = cnt[t*8+i];
  int sum = 0;
  #pragma unroll
  for (int i=0;i<8;++i) sum += loc[i];
  part[t] = sum;
  __syncthreads();
  for (int off=1; off<1024; off<<=1){
    int x = (t >= off) ? part[t-off] : 0;
    __syncthreads();
    part[t] += x;
    __syncthreads();
  }
  int run = (t > 0) ? part[t-1] : 0;
  #pragma unroll
  for (int i=0;i<8;++i){
    row_start[t*8+i] = run;
    cursor[t*8+i]    = run;
    run += loc[i];
  }
  if (t == 1023) row_start[8192] = run;
}

__global__ __launch_bounds__(256) void k_scatter(const int* __restrict__ receivers,
    int* __restrict__ cursor, int* __restrict__ perm)
{
  int e = blockIdx.x*256 + threadIdx.x;
  int r = receivers[e];
  int pos = atomicAdd(&cursor[r], 1);
  perm[pos] = e;
}

// geometry in RECEIVER-SORTED order: i = sorted index, e = perm[i]
__global__ __launch_bounds__(256) void k_geom(const float* __restrict__ pos,
    const int* __restrict__ senders, const int* __restrict__ receivers,
    const int* __restrict__ perm,
    float* __restrict__ sh8s, float* __restrict__ d_s,
    int* __restrict__ send_s, int* __restrict__ recv_s)
{
  const int i = blockIdx.x*256 + threadIdx.x;
  const int e = perm[i];
  const int s = senders[e], r = receivers[e];
  send_s[i] = s;
  recv_s[i] = r;
  float rx = (pos[r*3+0] - pos[s*3+0]) * 0.2f;
  float ry = (pos[r*3+1] - pos[s*3+1]) * 0.2f;
  float rz = (pos[r*3+2] - pos[s*3+2]) * 0.2f;
  float d  = sqrtf(rx*rx + ry*ry + rz*rz);
  d_s[i] = d;
  float iv = 1.0f / fmaxf(d, 1e-6f);
  float x = rx*iv, y = ry*iv, z = rz*iv;
  const float s3   = 1.7320508075688772f;
  const float s15  = 3.8729833462074170f;
  const float s5h  = 1.1180339887498949f;
  const float s15h = 1.9364916731037085f;
  sh8s[i*8+0] = s3*y;
  sh8s[i*8+1] = s3*z;
  sh8s[i*8+2] = s3*x;
  sh8s[i*8+3] = s15*x*y;
  sh8s[i*8+4] = s15*y*z;
  sh8s[i*8+5] = s5h*(3.f*z*z - 1.f);
  sh8s[i*8+6] = s15*x*z;
  sh8s[i*8+7] = s15h*(x*x - y*y);
}

// radial MLP in sorted order; 8 edges/block (4 waves x 2); lane = hidden unit
__global__ __launch_bounds__(256) void k_mlp(
    const float* __restrict__ d_s,
    const float* __restrict__ w1, const float* __restrict__ b1,
    const float* __restrict__ w2, const float* __restrict__ b2,
    ushortx* __restrict__ h2p)
{
  __shared__ float s_w2[4096];
  __shared__ float s_h1[4*64];
  const int tid = threadIdx.x, wv = tid>>6, lane = tid&63;
  const float PI = 3.14159265358979323846f;
  for (int i=tid;i<4096;i+=256) s_w2[i] = w2[i];
  __syncthreads();
  #pragma unroll
  for (int ee=0; ee<2; ++ee){
    const int i = blockIdx.x*8 + wv*2 + ee;
    const float d = d_s[i];
    float xr = fminf(fmaxf(d, 1e-4f), 1.0f);
    float ixr = 1.0f/xr;
    float acc = b1[lane];
    #pragma unroll
    for (int q=0;q<8;++q){
      float bs = 1.4142135623730951f * sinf((float)(q+1)*PI*xr) * ixr;
      acc = fmaf(bs, w1[q*64+lane], acc);
    }
    s_h1[wv*64+lane] = siluf(acc);
    __syncthreads();
    float acc2 = b2[lane];
    #pragma unroll
    for (int k=0;k<64;++k) acc2 = fmaf(s_h1[wv*64+k], s_w2[k*64+lane], acc2);
    float dc = fminf(fmaxf(d, 0.f), 1.f);
    float cut = 0.5f*(cosf(PI*dc) + 1.f);
    float h2 = siluf(acc2) * cut * 0.25f;     // fold envelope * 1/sqrt(avg_nn)
    h2p[(size_t)i*64+lane] = f2b(h2);
    __syncthreads();
  }
}

// w3 transpose + bf16 cast: w3t[n*64+k] = bf16(w3[k*960+n])
__global__ __launch_bounds__(256) void k_w3t(const float* __restrict__ w3,
                                             ushortx* __restrict__ w3t)
{
  int g = blockIdx.x*256 + threadIdx.x;   // g over 61440
  int n = g >> 6, k = g & 63;
  w3t[g] = f2b(w3[k*960 + n]);
}

// fused: MFMA edge-weight GEMM + sparse CG tensor product + per-node-range
// aggregation (LDS) + node update.  One block per 8 consecutive nodes.
// Identical to the R6 measured baseline except the CG contraction is the
// compile-time-sparse tp_combo version (zeros eliminated, literal coeffs).
__global__ __launch_bounds__(256) void k_aggmm(
    const float* __restrict__ featsIn, float* __restrict__ featsOut,
    const ushortx* __restrict__ h2p, const ushortx* __restrict__ w3t,
    const float* __restrict__ sh8s, const int* __restrict__ send_s,
    const int* __restrict__ recv_s, const int* __restrict__ rowst,
    const float* __restrict__ lin, const float* __restrict__ gw,
    const float* __restrict__ gb)
{
  __shared__ float   s_agg[NODE_BLK*FPN];   // 18432 B  (m-major per node)
  __shared__ ushortx s_w[16*SWROW];         // 30976 B
  __shared__ ushortx s_a[16*72];            //  2304 B

  const int tid  = threadIdx.x;
  const int wv   = tid >> 6;
  const int lane = tid & 63;
  const int n0   = blockIdx.x * NODE_BLK;
  const int beg  = rowst[n0];
  const int end  = rowst[n0 + NODE_BLK];

  for (int k = tid; k < NODE_BLK*FPN; k += 256) s_agg[k] = 0.f;
  __syncthreads();

  const int q = lane >> 4, mrow = lane & 15;

  for (int ebeg = beg; ebeg < end; ebeg += 16){
    // --- stage A tile (16 edges x 64 k, bf16) ---
    {
      int er = tid >> 4, seg = tid & 15;
      int i = ebeg + er;
      if (i >= end) i = end - 1;            // clamp: garbage rows unused later
      *(uint2*)&s_a[er*72 + seg*4] =
        *(const uint2*)&h2p[(size_t)i*64 + seg*4];
    }
    __syncthreads();

    // --- MFMA GEMM: wave wv covers cols wv*240 .. wv*240+239 ---
    short8 a0 = *(const short8*)&s_a[mrow*72 +      q*8];
    short8 a1 = *(const short8*)&s_a[mrow*72 + 32 + q*8];
    #pragma unroll
    for (int nt=0; nt<15; ++nt){
      const int col = wv*240 + nt*16 + mrow;     // B col n == C col
      short8 b0 = *(const short8*)&w3t[(size_t)col*64 +      q*8];
      short8 b1 = *(const short8*)&w3t[(size_t)col*64 + 32 + q*8];
      f32x4 acc = {0.f,0.f,0.f,0.f};
      acc = __builtin_amdgcn_mfma_f32_16x16x32_bf16(a0, b0, acc, 0, 0, 0);
      acc = __builtin_amdgcn_mfma_f32_16x16x32_bf16(a1, b1, acc, 0, 0, 0);
      #pragma unroll
      for (int r=0;r<4;++r)
        s_w[(q*4+r)*SWROW + col] = f2b(acc[r]);  // C row = (lane>>4)*4 + reg
    }
    __syncthreads();

    // --- sparse CG tensor product; wave wv owns slots wv*4+ee; lane = channel
    #pragma unroll
    for (int ee=0; ee<4; ++ee){
      const int slot = wv*4 + ee;
      const int i = ebeg + slot;
      if (i < end){
        const int s  = send_s[i];
        const int rl = recv_s[i] - n0;          // local node in [0,NODE_BLK)
        const float* fb = featsIn + (size_t)s*FPN;
        float X[9];
        #pragma unroll
        for (int r=0;r<9;++r) X[r] = fb[r*64 + lane];   // coalesced 256B rows
        float S[9];
        S[0] = 1.f;
        #pragma unroll
        for (int jj=0;jj<8;++jj) S[1+jj] = sh8s[(size_t)i*8+jj];
        float w[NPATHS];
        #pragma unroll
        for (int p=0;p<NPATHS;++p) w[p] = b2f(s_w[slot*SWROW + p*64 + lane]);
        float m[9];
        #pragma unroll
        for (int k=0;k<9;++k) m[k] = 0.f;

        tp_combo<0,0, 0,1>(X,S,w,m);
        tp_combo<0,1, 1,1>(X,S,w,m);
        tp_combo<0,2, 2,1>(X,S,w,m);
        tp_combo<1,0, 3,1>(X,S,w,m);
        tp_combo<1,1, 4,3>(X,S,w,m);
        tp_combo<1,2, 7,2>(X,S,w,m);
        tp_combo<2,0, 9,1>(X,S,w,m);
        tp_combo<2,1,10,2>(X,S,w,m);
        tp_combo<2,2,12,3>(X,S,w,m);

        float* ab = s_agg + rl*FPN;
        #pragma unroll
        for (int r=0;r<9;++r) atomicAdd(&ab[r*64 + lane], m[r]);   // stride-1
      }
    }
    __syncthreads();
  }

  // --- node update: wave wv handles nodes wv*2 .. wv*2+1 ---
  #pragma unroll
  for (int k=0;k<2;++k){
    const int ln = wv*2 + k;
    const int n  = n0 + ln;
    const float* ag = s_agg + ln*FPN;
    float y[9];
    #pragma unroll
    for (int j=0;j<9;++j) y[j] = 0.f;
    for (int c=0;c<64;++c){
      float l0 = lin[          c*64 + lane];
      float l1 = lin[4096    + c*64 + lane];
      float l2 = lin[8192    + c*64 + lane];
      y[0] = fmaf(ag[c], l0, y[0]);
      #pragma unroll
      for (int mm=0;mm<3;++mm) y[1+mm] = fmaf(ag[(1+mm)*64 + c], l1, y[1+mm]);
      #pragma unroll
      for (int mm=0;mm<5;++mm) y[4+mm] = fmaf(ag[(4+mm)*64 + c], l2, y[4+mm]);
    }
    const size_t base = (size_t)n*FPN;
    float f0 = featsIn[base + lane] + siluf(y[0]);
    featsOut[base + lane] = f0;
    float a1 = gb[lane], a2 = gb[64 + lane];
    for (int c=0;c<64;++c){
      float fc = __shfl(f0, c);
      a1 = fmaf(fc, gw[        c*64 + lane], a1);
      a2 = fmaf(fc, gw[4096 +  c*64 + lane], a2);
    }
    float g1 = sigmf(a1), g2 = sigmf(a2);
    #pragma unroll
    for (int mm=0;mm<3;++mm)
      featsOut[base + (1+mm)*64 + lane] = featsIn[base + (1+mm)*64 + lane] + g1*y[1+mm];
    #pragma unroll
    for (int mm=0;mm<5;++mm)
      featsOut[base + (4+mm)*64 + lane] = featsIn[base + (4+mm)*64 + lane] + g2*y[4+mm];
  }
}

// ---------------- fallback (round-0 verified path, ch-major layout) --------
__global__ __launch_bounds__(64) void k_init_fb(const int* __restrict__ species,
    const float* __restrict__ embed, const float* __restrict__ wproj,
    float* __restrict__ feats)
{
  const int n = blockIdx.x, c = threadIdx.x;
  const int sp = species[n];
  float acc = 0.f;
  #pragma unroll
  for (int q=0;q<32;++q) acc += embed[sp*32+q]*wproj[q*64+c];
  feats[n*FPN + c] = acc;
  #pragma unroll
  for (int j=0;j<8;++j) feats[n*FPN + 64 + j*64 + c] = 0.f;
}

__global__ __launch_bounds__(256) void k_out_fb(const float* __restrict__ feats,
                                                float* __restrict__ out)
{
  const int n = blockIdx.x;
  for (int j = threadIdx.x; j < FPN; j += 256){
    float sc = (j < 64) ? 1.0f : ((j < 256) ? 0.5f : 0.25f);
    out[n*FPN + j] = feats[n*FPN + j] * sc;
  }
}

__global__ __launch_bounds__(256) void k_edge_fb(
    const float* __restrict__ pos,
    const int* __restrict__ senders, const int* __restrict__ receivers,
    const float* __restrict__ w1, const float* __restrict__ b1,
    const float* __restrict__ w2, const float* __restrict__ b2,
    const float* __restrict__ w3,
    const float* __restrict__ feats, float* __restrict__ agg,
    const CGTable cg)
{
  __shared__ float s_h1[16*64];
  __shared__ float s_h2[16*64];
  __shared__ float s_w3[8*960];
  __shared__ float s_sh[16][8];
  __shared__ float s_cut[16];

  const int tid  = threadIdx.x;
  const int wave = tid >> 6;
  const int lane = tid & 63;
  const int ebase = blockIdx.x * 16;
  const float PI = 3.14159265358979323846f;

  #pragma unroll
  for (int ee=0; ee<4; ++ee){
    const int slot = wave*4 + ee;
    const int e = ebase + slot;
    const int s = senders[e], r = receivers[e];
    float rx = (pos[r*3+0] - pos[s*3+0]) * 0.2f;
    float ry = (pos[r*3+1] - pos[s*3+1]) * 0.2f;
    float rz = (pos[r*3+2] - pos[s*3+2]) * 0.2f;
    float d  = sqrtf(rx*rx + ry*ry + rz*rz);
    float iv = 1.0f / fmaxf(d, 1e-6f);
    float x = rx*iv, y = ry*iv, z = rz*iv;
    if (lane == 0){
      const float s3   = 1.7320508075688772f;
      const float s15  = 3.8729833462074170f;
      const float s5h  = 1.1180339887498949f;
      const float s15h = 1.9364916731037085f;
      s_sh[slot][0] = s3*y;  s_sh[slot][1] = s3*z;  s_sh[slot][2] = s3*x;
      s_sh[slot][3] = s15*x*y; s_sh[slot][4] = s15*y*z;
      s_sh[slot][5] = s5h*(3.f*z*z - 1.f);
      s_sh[slot][6] = s15*x*z; s_sh[slot][7] = s15h*(x*x - y*y);
      float dc = fminf(fmaxf(d, 0.f), 1.f);
      s_cut[slot] = 0.5f*(cosf(PI*dc) + 1.f);
    }
    float xr = fminf(fmaxf(d, 1e-4f), 1.0f);
    float ixr = 1.0f/xr;
    float acc = b1[lane];
    #pragma unroll
    for (int q=0;q<8;++q)
      acc += 1.4142135623730951f * sinf((float)(q+1)*PI*xr) * ixr * w1[q*64 + lane];
    s_h1[slot*64 + lane] = siluf(acc);
  }
  __syncthreads();
  #pragma unroll
  for (int ee=0; ee<4; ++ee){
    const int slot = wave*4 + ee;
    float acc = b2[lane];
    #pragma unroll
    for (int k=0;k<64;++k) acc += s_h1[slot*64+k] * w2[k*64+lane];
    s_h2[slot*64+lane] = siluf(acc);
  }
  __syncthreads();

  float wgt[NPATHS][4];
  #pragma unroll
  for (int p=0;p<NPATHS;++p){ wgt[p][0]=wgt[p][1]=wgt[p][2]=wgt[p][3]=0.f; }
  for (int kc=0;kc<8;++kc){
    #pragma unroll
    for (int rr=0;rr<8;++rr){
      #pragma unroll
      for (int jj=0;jj<4;++jj){
        int col = jj*256 + tid;
        if (col < 960) s_w3[rr*960+col] = w3[(kc*8+rr)*960+col];
      }
    }
    __syncthreads();
    #pragma unroll
    for (int kk=0;kk<8;++kk){
      float h2v[4];
      #pragma unroll
      for (int ee=0;ee<4;++ee) h2v[ee] = s_h2[(wave*4+ee)*64 + kc*8+kk];
      #pragma unroll
      for (int p=0;p<NPATHS;++p){
        float wv = s_w3[kk*960 + p*64 + lane];
        #pragma unroll
        for (int ee=0;ee<4;++ee) wgt[p][ee] = fmaf(h2v[ee], wv, wgt[p][ee]);
      }
    }
    __syncthreads();
  }
  #pragma unroll
  for (int ee=0;ee<4;++ee){
    float f = s_cut[wave*4+ee] * 0.25f;
    #pragma unroll
    for (int p=0;p<NPATHS;++p) wgt[p][ee] *= f;
  }
  #pragma unroll
  for (int ee=0;ee<4;++ee){
    const int slot = wave*4 + ee;
    const int e = ebase + slot;
    const int s = senders[e];
    const int r = receivers[e];
    const int sb = s*FPN;
    float X[9], S[9], msg[9];
    X[0] = feats[sb + lane];
    #pragma unroll
    for (int mm=0;mm<3;++mm) X[1+mm] = feats[sb + 64  + lane*3 + mm];
    #pragma unroll
    for (int mm=0;mm<5;++mm) X[4+mm] = feats[sb + 256 + lane*5 + mm];
    S[0] = 1.f;
    #pragma unroll
    for (int j=0;j<8;++j) S[1+j] = s_sh[slot][j];
    #pragma unroll
    for (int k=0;k<9;++k) msg[k] = 0.f;
    #pragma unroll
    for (int p=0;p<NPATHS;++p){
      const int l1=PL1[p], l2=PL2[p], l3=PL3[p];
      const int n2=2*l2+1, n3=2*l3+1;
      const float wp = wgt[p][ee];
      #pragma unroll
      for (int i=0;i<2*l1+1;++i){
        #pragma unroll
        for (int j=0;j<n2;++j){
          float t = wp * X[BOFF[l1]+i] * S[BOFF[l2]+j];
          #pragma unroll
          for (int k=0;k<n3;++k)
            msg[BOFF[l3]+k] = fmaf(cg.v[CGOFF[p] + (i*n2+j)*n3 + k], t, msg[BOFF[l3]+k]);
        }
      }
    }
    const int rb = r*FPN;
    unsafeAtomicAdd(&agg[rb + lane], msg[0]);
    #pragma unroll
    for (int mm=0;mm<3;++mm) unsafeAtomicAdd(&agg[rb + 64  + lane*3 + mm], msg[1+mm]);
    #pragma unroll
    for (int mm=0;mm<5;++mm) unsafeAtomicAdd(&agg[rb + 256 + lane*5 + mm], msg[4+mm]);
  }
}

__global__ __launch_bounds__(64) void k_node_fb(
    float* __restrict__ feats, const float* __restrict__ agg,
    const float* __restrict__ lin, const float* __restrict__ gw,
    const float* __restrict__ gb)
{
  __shared__ float sf0[64];
  const int n = blockIdx.x, d = threadIdx.x;
  const int base = n*FPN;
  float y[9];
  #pragma unroll
  for (int k=0;k<9;++k) y[k]=0.f;
  for (int c=0;c<64;++c){
    float l0 = lin[          c*64 + d];
    float l1 = lin[4096    + c*64 + d];
    float l2 = lin[8192    + c*64 + d];
    y[0] = fmaf(agg[base + c], l0, y[0]);
    #pragma unroll
    for (int mm=0;mm<3;++mm) y[1+mm] = fmaf(agg[base + 64  + c*3 + mm], l1, y[1+mm]);
    #pragma unroll
    for (int mm=0;mm<5;++mm) y[4+mm] = fmaf(agg[base + 256 + c*5 + mm], l2, y[4+mm]);
  }
  float f0 = feats[base + d] + siluf(y[0]);
  feats[base + d] = f0;
  sf0[d] = f0;
  __syncthreads();
  {
    float acc = gb[d];
    for (int c=0;c<64;++c) acc = fmaf(sf0[c], gw[c*64 + d], acc);
    float g = sigmf(acc);
    #pragma unroll
    for (int mm=0;mm<3;++mm) feats[base + 64 + d*3 + mm] += g*y[1+mm];
  }
  {
    float acc = gb[64 + d];
    for (int c=0;c<64;++c) acc = fmaf(sf0[c], gw[4096 + c*64 + d], acc);
    float g = sigmf(acc);
    #pragma unroll
    for (int mm=0;mm<5;++mm) feats[base + 256 + d*5 + mm] += g*y[4+mm];
  }
}

// ---------------- launch ----------------
extern "C" void kernel_launch(void* const* d_in, const int* in_sizes, int n_in,
                              void* d_out, int out_size, void* d_ws, size_t ws_size,
                              hipStream_t stream)
{
  const float* pos      = (const float*)d_in[0];
  const int*   species  = (const int*)  d_in[1];
  const int*   senders  = (const int*)  d_in[2];
  const int*   receivers= (const int*)  d_in[3];
  const float* embed    = (const float*)d_in[4];
  const float* wproj    = (const float*)d_in[5];
  const float* w1       = (const float*)d_in[6];
  const float* b1       = (const float*)d_in[7];
  const float* w2       = (const float*)d_in[8];
  const float* b2       = (const float*)d_in[9];
  const float* w3       = (const float*)d_in[10];
  const float* lin      = (const float*)d_in[11];
  const float* gw       = (const float*)d_in[12];
  const float* gb       = (const float*)d_in[13];

  // ws layout (main path) — ~61 MB total
  char* p = (char*)d_ws;
  size_t off = 0;
  auto alloc = [&](size_t bytes)->char*{
    char* r = p + off;
    off += (bytes + 255) & ~(size_t)255;
    return r;
  };
  float*   featsA  = (float*)  alloc((size_t)N_NODES*FPN*4);
  float*   featsB  = (float*)  alloc((size_t)N_NODES*FPN*4);
  int*     cnt     = (int*)    alloc(N_NODES*4);
  int*     cursor  = (int*)    alloc(N_NODES*4);
  int*     rowst   = (int*)    alloc((N_NODES+1)*4);
  int*     perm    = (int*)    alloc((size_t)N_EDGES*4);
  int*     send_s  = (int*)    alloc((size_t)N_EDGES*4);
  int*     recv_s  = (int*)    alloc((size_t)N_EDGES*4);
  float*   d_sArr  = (float*)  alloc((size_t)N_EDGES*4);
  float*   sh8s    = (float*)  alloc((size_t)N_EDGES*8*4);
  ushortx* h2p     = (ushortx*)alloc((size_t)N_EDGES*64*2);
  ushortx* w3t     = (ushortx*)alloc((size_t)960*64*2);
  const size_t need_main = off;

  if (ws_size >= need_main){
    hipMemsetAsync(cnt, 0, N_NODES*4, stream);
    hipLaunchKernelGGL(k_hist,    dim3(N_EDGES/256), dim3(256), 0, stream, receivers, cnt);
    hipLaunchKernelGGL(k_scan,    dim3(1), dim3(1024), 0, stream, cnt, rowst, cursor);
    hipLaunchKernelGGL(k_scatter, dim3(N_EDGES/256), dim3(256), 0, stream, receivers, cursor, perm);
    hipLaunchKernelGGL(k_geom,    dim3(N_EDGES/256), dim3(256), 0, stream,
                       pos, senders, receivers, perm, sh8s, d_sArr, send_s, recv_s);
    hipLaunchKernelGGL(k_init,    dim3(N_NODES), dim3(64), 0, stream,
                       species, embed, wproj, featsA);
    for (int L=0; L<2; ++L){
      const float* fin  = (L == 0) ? featsA : featsB;
      float*       fout = (L == 0) ? featsB : featsA;
      hipLaunchKernelGGL(k_mlp,  dim3(N_EDGES/8), dim3(256), 0, stream,
                         d_sArr, w1 + L*512, b1 + L*64, w2 + L*4096, b2 + L*64, h2p);
      hipLaunchKernelGGL(k_w3t,  dim3(240), dim3(256), 0, stream, w3 + (size_t)L*61440, w3t);
      hipLaunchKernelGGL(k_aggmm, dim3(N_NODES/NODE_BLK), dim3(256), 0, stream,
                         fin, fout, h2p, w3t, sh8s, send_s, recv_s, rowst,
                         lin + L*3*64*64, gw + L*2*64*64, gb + L*2*64);
    }
    hipLaunchKernelGGL(k_out_t, dim3(N_NODES), dim3(64), 0, stream, featsA, (float*)d_out);
  } else {
    // fallback: round-0 verified path (needs only feats + agg = 37.7 MB)
    float* feats = (float*)d_ws;
    float* agg   = feats + (size_t)N_NODES*FPN;
    hipLaunchKernelGGL(k_init_fb, dim3(N_NODES), dim3(64), 0, stream,
                       species, embed, wproj, feats);
    for (int L=0; L<2; ++L){
      hipMemsetAsync(agg, 0, (size_t)N_NODES*FPN*sizeof(float), stream);
      hipLaunchKernelGGL(k_edge_fb, dim3(N_EDGES/16), dim3(256), 0, stream,
                         pos, senders, receivers,
                         w1 + L*512, b1 + L*64, w2 + L*4096, b2 + L*64,
                         w3 + (size_t)L*61440, feats, agg, CGC);
      hipLaunchKernelGGL(k_node_fb, dim3(N_NODES), dim3(64), 0, stream,
                         feats, agg, lin + L*3*64*64, gw + L*2*64*64, gb + L*2*64);
    }
    hipLaunchKernelGGL(k_out_fb, dim3(N_NODES), dim3(256), 0, stream, feats, (float*)d_out);
  }
}